// Round 2
// baseline (521.786 us; speedup 1.0000x reference)
//
#include <hip/hip_runtime.h>
#include <hip/hip_bf16.h>

#define B_ 8
#define L_ 512
#define N_ 2048
#define C_ 1024
#define D_ 128

typedef __attribute__((ext_vector_type(8))) short    short8;   // 8 x bf16 bits
typedef __attribute__((ext_vector_type(8))) _Float16 half8;
typedef __attribute__((ext_vector_type(4))) float    floatx4;

static __device__ __forceinline__ float s2f(short s) {
    return __uint_as_float(((unsigned)(unsigned short)s) << 16);
}
static __device__ __forceinline__ short f2bf(float f) {
    union { __hip_bfloat16 h; short s; } u;
    u.h = __float2bfloat16(f);
    return u.s;
}

struct F8 { float v[8]; };

// Load 8 consecutive elements from a raw input buffer that is either fp32 or
// bf16 (flag is wave-uniform), returning fp32 values.
static __device__ __forceinline__ F8 load8(const void* raw, long off, int is_bf16) {
    F8 r;
    if (is_bf16) {
        short8 x = *reinterpret_cast<const short8*>((const short*)raw + off);
        #pragma unroll
        for (int i = 0; i < 8; ++i) r.v[i] = s2f(x[i]);
    } else {
        const float* p = (const float*)raw + off;
        float4 a = *reinterpret_cast<const float4*>(p);
        float4 b = *reinterpret_cast<const float4*>(p + 4);
        r.v[0]=a.x; r.v[1]=a.y; r.v[2]=a.z; r.v[3]=a.w;
        r.v[4]=b.x; r.v[5]=b.y; r.v[6]=b.z; r.v[7]=b.w;
    }
    return r;
}

static __device__ __forceinline__ float bias_at(const void* raw, int d, int is_bf16) {
    return is_bf16 ? s2f(((const short*)raw)[d]) : ((const float*)raw)[d];
}

// ---------------------------------------------------------------------------
// Dtype detection: read first 256 words of teacher_features. If the low 16
// bits of each word decode to an in-range bf16 (they are bf16 samples of
// N(0,1) in the bf16 world; random fp32 mantissa bits in the fp32 world),
// the inputs are bf16. flag=1 -> bf16 inputs/outputs, flag=0 -> fp32.
// ---------------------------------------------------------------------------
__global__ void detect_kernel(const unsigned* __restrict__ words, int* __restrict__ flag) {
    int cnt = 0;
    for (int i = threadIdx.x; i < 256; i += 64) {
        float lowv = __uint_as_float(words[i] << 16);
        float a = fabsf(lowv);
        if (a >= 1e-5f && a <= 100.0f) cnt++;
    }
    #pragma unroll
    for (int off = 32; off; off >>= 1) cnt += __shfl_down(cnt, off);
    if (threadIdx.x == 0) flag[0] = (cnt > 128) ? 1 : 0;
}

// ---------------------------------------------------------------------------
// Convert a raw (fp32 or bf16) array to bf16 bits.
// ---------------------------------------------------------------------------
__global__ __launch_bounds__(256) void cvt_kernel(const void* __restrict__ in_raw,
                                                  short* __restrict__ out, long n,
                                                  const int* __restrict__ flag) {
    const int is_bf16 = *flag;
    long i = ((long)blockIdx.x * 256 + threadIdx.x) * 8;
    if (i >= n) return;
    F8 x = load8(in_raw, i, is_bf16);
    short8 o;
    #pragma unroll
    for (int j = 0; j < 8; ++j) o[j] = f2bf(x.v[j]);
    *reinterpret_cast<short8*>(out + i) = o;
}

// ---------------------------------------------------------------------------
// Split a raw weight array into bf16 hi + bf16 lo (residual). In the bf16
// world lo is exactly zero.
// ---------------------------------------------------------------------------
__global__ __launch_bounds__(256) void wsplit_kernel(const void* __restrict__ in_raw,
                                                     short* __restrict__ hi,
                                                     short* __restrict__ lo, long n,
                                                     const int* __restrict__ flag) {
    const int is_bf16 = *flag;
    long i = ((long)blockIdx.x * 256 + threadIdx.x) * 8;
    if (i >= n) return;
    F8 x = load8(in_raw, i, is_bf16);
    short8 h8, l8;
    #pragma unroll
    for (int j = 0; j < 8; ++j) {
        short h = f2bf(x.v[j]);
        h8[j] = h;
        l8[j] = f2bf(x.v[j] - s2f(h));
    }
    *reinterpret_cast<short8*>(hi + i) = h8;
    *reinterpret_cast<short8*>(lo + i) = l8;
}

// ---------------------------------------------------------------------------
// Kernel 1: Q = F @ Wq^T + bq ; K = F @ Wk^T + bk (stored fp16).
// Split-bf16: acc = Fhi*Whi + Flo*Whi + Fhi*Wlo (lo*lo dropped).
// Block 256 = 4 waves; block covers 16 rows x (Q 128 cols | K 128 cols).
// ---------------------------------------------------------------------------
__global__ __launch_bounds__(256) void proj_kernel(
    const void* __restrict__ Fraw,    // [B*N, C] fp32 or bf16
    const short* __restrict__ Whi_q, const short* __restrict__ Wlo_q,
    const void* __restrict__ bq_raw,
    const short* __restrict__ Whi_k, const short* __restrict__ Wlo_k,
    const void* __restrict__ bk_raw,
    _Float16* __restrict__ Q, _Float16* __restrict__ K,
    const int* __restrict__ flag)
{
    const int is_bf16 = *flag;
    const int wave = threadIdx.x >> 6;
    const int lane = threadIdx.x & 63;
    const int quad = lane >> 4;
    const int l16  = lane & 15;
    const long row0 = (long)blockIdx.x * 16;

    const bool isK = (wave >= 2);
    const short* Whi = isK ? Whi_k : Whi_q;
    const short* Wlo = isK ? Wlo_k : Wlo_q;
    const void* braw = isK ? bk_raw : bq_raw;
    _Float16* Out    = isK ? K : Q;
    const int dbase  = (wave & 1) * 64;

    floatx4 acc[4] = {};
    const long arow = (row0 + l16) * (long)C_ + quad * 8;

    for (int s = 0; s < 32; ++s) {
        F8 x = load8(Fraw, arow + s * 32, is_bf16);
        short8 ahi, alo;
        #pragma unroll
        for (int j = 0; j < 8; ++j) {
            short h = f2bf(x.v[j]);
            ahi[j] = h;
            alo[j] = f2bf(x.v[j] - s2f(h));
        }
        #pragma unroll
        for (int t = 0; t < 4; ++t) {
            const long woff = (long)(dbase + t * 16 + l16) * C_ + s * 32 + quad * 8;
            short8 bhi = *reinterpret_cast<const short8*>(Whi + woff);
            short8 blo = *reinterpret_cast<const short8*>(Wlo + woff);
            acc[t] = __builtin_amdgcn_mfma_f32_16x16x32_bf16(ahi, bhi, acc[t], 0, 0, 0);
            acc[t] = __builtin_amdgcn_mfma_f32_16x16x32_bf16(alo, bhi, acc[t], 0, 0, 0);
            acc[t] = __builtin_amdgcn_mfma_f32_16x16x32_bf16(ahi, blo, acc[t], 0, 0, 0);
        }
    }

    #pragma unroll
    for (int t = 0; t < 4; ++t) {
        const int d = dbase + t * 16 + l16;
        const float bv = bias_at(braw, d, is_bf16);
        #pragma unroll
        for (int r = 0; r < 4; ++r) {
            const long row = row0 + quad * 4 + r;
            Out[row * D_ + d] = (_Float16)(acc[t][r] + bv);
        }
    }
}

// ---------------------------------------------------------------------------
// Kernel 2: E = Q K^T (fp16 MFMA), softmax rows -> A (bf16 bits).
// Block 512 = 8 waves, covers 16 rows x full 2048 cols; E register-resident.
// ---------------------------------------------------------------------------
__global__ __launch_bounds__(512) void attn_kernel(
    const _Float16* __restrict__ Q,   // [B, N, D]
    const _Float16* __restrict__ K,   // [B, N, D]
    short* __restrict__ A)            // [B, N, N] bf16 bits
{
    const int b    = blockIdx.y;
    const int i0   = blockIdx.x * 16;
    const int wave = threadIdx.x >> 6;
    const int lane = threadIdx.x & 63;
    const int quad = lane >> 4;
    const int l16  = lane & 15;

    const _Float16* Qb = Q + (long)b * N_ * D_;
    const _Float16* Kb = K + (long)b * N_ * D_;

    half8 a[4];
    #pragma unroll
    for (int s = 0; s < 4; ++s)
        a[s] = *reinterpret_cast<const half8*>(Qb + (long)(i0 + l16) * D_ + s * 32 + quad * 8);

    floatx4 acc[16];
    #pragma unroll
    for (int t = 0; t < 16; ++t) acc[t] = (floatx4){0.f, 0.f, 0.f, 0.f};

    const int jbase = wave * 256;
    #pragma unroll
    for (int t = 0; t < 16; ++t) {
        const _Float16* krow = Kb + (long)(jbase + t * 16 + l16) * D_ + quad * 8;
        #pragma unroll
        for (int s = 0; s < 4; ++s) {
            half8 bf = *reinterpret_cast<const half8*>(krow + s * 32);
            acc[t] = __builtin_amdgcn_mfma_f32_16x16x32_f16(a[s], bf, acc[t], 0, 0, 0);
        }
    }

    __shared__ float red_max[16][8];
    __shared__ float red_sum[16][8];

    float gmax[4];
    #pragma unroll
    for (int r = 0; r < 4; ++r) {
        float m = -1e30f;
        #pragma unroll
        for (int t = 0; t < 16; ++t) m = fmaxf(m, acc[t][r]);
        m = fmaxf(m, __shfl_xor(m, 1));
        m = fmaxf(m, __shfl_xor(m, 2));
        m = fmaxf(m, __shfl_xor(m, 4));
        m = fmaxf(m, __shfl_xor(m, 8));
        if (l16 == 0) red_max[quad * 4 + r][wave] = m;
    }
    __syncthreads();
    #pragma unroll
    for (int r = 0; r < 4; ++r) {
        float m = red_max[quad * 4 + r][0];
        #pragma unroll
        for (int w = 1; w < 8; ++w) m = fmaxf(m, red_max[quad * 4 + r][w]);
        gmax[r] = m;
    }

    #pragma unroll
    for (int r = 0; r < 4; ++r) {
        float s = 0.f;
        #pragma unroll
        for (int t = 0; t < 16; ++t) {
            float e = __expf(acc[t][r] - gmax[r]);
            acc[t][r] = e;
            s += e;
        }
        s += __shfl_xor(s, 1);
        s += __shfl_xor(s, 2);
        s += __shfl_xor(s, 4);
        s += __shfl_xor(s, 8);
        if (l16 == 0) red_sum[quad * 4 + r][wave] = s;
    }
    __syncthreads();

    float inv[4];
    #pragma unroll
    for (int r = 0; r < 4; ++r) {
        float s = 0.f;
        #pragma unroll
        for (int w = 0; w < 8; ++w) s += red_sum[quad * 4 + r][w];
        inv[r] = 1.0f / s;
    }

    short* Ab = A + (long)b * N_ * N_;
    #pragma unroll
    for (int t = 0; t < 16; ++t) {
        const int j = jbase + t * 16 + l16;
        #pragma unroll
        for (int r = 0; r < 4; ++r) {
            Ab[(long)(i0 + quad * 4 + r) * N_ + j] = f2bf(acc[t][r] * inv[r]);
        }
    }
}

// ---------------------------------------------------------------------------
// Kernel 3: x_m[b,l,m] = sum_n logits[b,l,n] * A[b,m,n]  (NT GEMM, bf16 MFMA)
// Block 256 = 4 waves; wave tile 32x64; block tile 32 rows x 256 cols.
// Output dtype chosen by flag (fp32 world -> float, bf16 world -> bf16).
// ---------------------------------------------------------------------------
__global__ __launch_bounds__(256) void xm_kernel(
    const short* __restrict__ Lg,   // [B, L, N] bf16 bits
    const short* __restrict__ A,    // [B, N, N] bf16 bits
    void* __restrict__ OutRaw,
    const int* __restrict__ flag)
{
    const int is_bf16 = *flag;
    const int b    = blockIdx.z;
    const int r0   = blockIdx.x * 32;
    const int wave = threadIdx.x >> 6;
    const int lane = threadIdx.x & 63;
    const int quad = lane >> 4;
    const int l16  = lane & 15;
    const int c0   = blockIdx.y * 256 + wave * 64;

    const short* Lb = Lg + (long)b * L_ * N_;
    const short* Ab = A + (long)b * N_ * N_;

    floatx4 acc[2][4] = {};

    const short* a0p = Lb + (long)(r0 + l16) * N_ + quad * 8;
    const short* a1p = Lb + (long)(r0 + 16 + l16) * N_ + quad * 8;
    const short* bp  = Ab + (long)(c0 + l16) * N_ + quad * 8;

    for (int s = 0; s < 64; ++s) {
        const int k0 = s * 32;
        short8 a0 = *reinterpret_cast<const short8*>(a0p + k0);
        short8 a1 = *reinterpret_cast<const short8*>(a1p + k0);
        #pragma unroll
        for (int t = 0; t < 4; ++t) {
            short8 bb = *reinterpret_cast<const short8*>(bp + (long)t * 16 * N_ + k0);
            acc[0][t] = __builtin_amdgcn_mfma_f32_16x16x32_bf16(a0, bb, acc[0][t], 0, 0, 0);
            acc[1][t] = __builtin_amdgcn_mfma_f32_16x16x32_bf16(a1, bb, acc[1][t], 0, 0, 0);
        }
    }

    if (is_bf16) {
        short* Ob = (short*)OutRaw + (long)b * L_ * N_;
        #pragma unroll
        for (int u = 0; u < 2; ++u)
            #pragma unroll
            for (int t = 0; t < 4; ++t)
                #pragma unroll
                for (int r = 0; r < 4; ++r) {
                    const long row = r0 + u * 16 + quad * 4 + r;
                    const int  col = c0 + t * 16 + l16;
                    Ob[row * N_ + col] = f2bf(acc[u][t][r]);
                }
    } else {
        float* Ob = (float*)OutRaw + (long)b * L_ * N_;
        #pragma unroll
        for (int u = 0; u < 2; ++u)
            #pragma unroll
            for (int t = 0; t < 4; ++t)
                #pragma unroll
                for (int r = 0; r < 4; ++r) {
                    const long row = r0 + u * 16 + quad * 4 + r;
                    const int  col = c0 + t * 16 + l16;
                    Ob[row * N_ + col] = acc[u][t][r];
                }
    }
}

// ---------------------------------------------------------------------------
extern "C" void kernel_launch(void* const* d_in, const int* in_sizes, int n_in,
                              void* d_out, int out_size, void* d_ws, size_t ws_size,
                              hipStream_t stream) {
    const void* logits_raw = d_in[0];  // [B,L,N]
    const void* feats_raw  = d_in[1];  // [B,N,C]
    const void* wq_raw     = d_in[2];  // [D,C]
    const void* bq_raw     = d_in[3];  // [D]
    const void* wk_raw     = d_in[4];  // [D,C]
    const void* bk_raw     = d_in[5];  // [D]

    char* ws = (char*)d_ws;
    size_t off = 0;
    int* flag = (int*)(ws + off);           off += 256;
    short* logb = (short*)(ws + off);       off += (size_t)B_ * L_ * N_ * 2;   // 16 MB
    short* whq = (short*)(ws + off);        off += (size_t)D_ * C_ * 2;
    short* wlq = (short*)(ws + off);        off += (size_t)D_ * C_ * 2;
    short* whk = (short*)(ws + off);        off += (size_t)D_ * C_ * 2;
    short* wlk = (short*)(ws + off);        off += (size_t)D_ * C_ * 2;
    _Float16* Q = (_Float16*)(ws + off);    off += (size_t)B_ * N_ * D_ * 2;   // 4 MB
    _Float16* K = (_Float16*)(ws + off);    off += (size_t)B_ * N_ * D_ * 2;   // 4 MB
    short* A = (short*)(ws + off);          off += (size_t)B_ * N_ * N_ * 2;   // 67 MB

    hipLaunchKernelGGL(detect_kernel, dim3(1), dim3(64), 0, stream,
                       (const unsigned*)feats_raw, flag);
    hipLaunchKernelGGL(cvt_kernel, dim3((B_ * L_ * N_) / (256 * 8)), dim3(256), 0, stream,
                       logits_raw, logb, (long)B_ * L_ * N_, flag);
    hipLaunchKernelGGL(wsplit_kernel, dim3((D_ * C_) / (256 * 8)), dim3(256), 0, stream,
                       wq_raw, whq, wlq, (long)D_ * C_, flag);
    hipLaunchKernelGGL(wsplit_kernel, dim3((D_ * C_) / (256 * 8)), dim3(256), 0, stream,
                       wk_raw, whk, wlk, (long)D_ * C_, flag);
    hipLaunchKernelGGL(proj_kernel, dim3(B_ * N_ / 16), dim3(256), 0, stream,
                       feats_raw, whq, wlq, bq_raw, whk, wlk, bk_raw, Q, K, flag);
    hipLaunchKernelGGL(attn_kernel, dim3(N_ / 16, B_), dim3(512), 0, stream,
                       Q, K, A);
    hipLaunchKernelGGL(xm_kernel, dim3(L_ / 32, N_ / 256, B_), dim3(256), 0, stream,
                       logb, A, d_out, flag);
}

// Round 3
// 336.248 us; speedup vs baseline: 1.5518x; 1.5518x over previous
//
#include <hip/hip_runtime.h>
#include <hip/hip_bf16.h>

#define B_ 8
#define L_ 512
#define N_ 2048
#define C_ 1024
#define D_ 128

typedef __attribute__((ext_vector_type(8))) short    short8;   // 8 x bf16 bits
typedef __attribute__((ext_vector_type(8))) _Float16 half8;
typedef __attribute__((ext_vector_type(4))) float    floatx4;

static __device__ __forceinline__ float s2f(short s) {
    return __uint_as_float(((unsigned)(unsigned short)s) << 16);
}
static __device__ __forceinline__ short f2bf(float f) {
    union { __hip_bfloat16 h; short s; } u;
    u.h = __float2bfloat16(f);
    return u.s;
}

struct F8 { float v[8]; };

// Load 8 consecutive elements from a raw input buffer that is either fp32 or
// bf16 (flag is wave-uniform), returning fp32 values.
static __device__ __forceinline__ F8 load8(const void* raw, long off, int is_bf16) {
    F8 r;
    if (is_bf16) {
        short8 x = *reinterpret_cast<const short8*>((const short*)raw + off);
        #pragma unroll
        for (int i = 0; i < 8; ++i) r.v[i] = s2f(x[i]);
    } else {
        const float* p = (const float*)raw + off;
        float4 a = *reinterpret_cast<const float4*>(p);
        float4 b = *reinterpret_cast<const float4*>(p + 4);
        r.v[0]=a.x; r.v[1]=a.y; r.v[2]=a.z; r.v[3]=a.w;
        r.v[4]=b.x; r.v[5]=b.y; r.v[6]=b.z; r.v[7]=b.w;
    }
    return r;
}

static __device__ __forceinline__ float bias_at(const void* raw, int d, int is_bf16) {
    return is_bf16 ? s2f(((const short*)raw)[d]) : ((const float*)raw)[d];
}

static __device__ __forceinline__ void load_lds16(const short* g, short* l) {
    __builtin_amdgcn_global_load_lds(
        (const __attribute__((address_space(1))) void*)g,
        (__attribute__((address_space(3))) void*)l, 16, 0, 0);
}

// ---------------------------------------------------------------------------
// Dtype detection (fp32 vs bf16 world), as round 2.
// ---------------------------------------------------------------------------
__global__ void detect_kernel(const unsigned* __restrict__ words, int* __restrict__ flag) {
    int cnt = 0;
    for (int i = threadIdx.x; i < 256; i += 64) {
        float lowv = __uint_as_float(words[i] << 16);
        float a = fabsf(lowv);
        if (a >= 1e-5f && a <= 100.0f) cnt++;
    }
    #pragma unroll
    for (int off = 32; off; off >>= 1) cnt += __shfl_down(cnt, off);
    if (threadIdx.x == 0) flag[0] = (cnt > 128) ? 1 : 0;
}

// ---------------------------------------------------------------------------
// raw (fp32|bf16) -> bf16 bits
// ---------------------------------------------------------------------------
__global__ __launch_bounds__(256) void cvt_kernel(const void* __restrict__ in_raw,
                                                  short* __restrict__ out, long n,
                                                  const int* __restrict__ flag) {
    const int is_bf16 = *flag;
    long i = ((long)blockIdx.x * 256 + threadIdx.x) * 8;
    if (i >= n) return;
    F8 x = load8(in_raw, i, is_bf16);
    short8 o;
    #pragma unroll
    for (int j = 0; j < 8; ++j) o[j] = f2bf(x.v[j]);
    *reinterpret_cast<short8*>(out + i) = o;
}

// ---------------------------------------------------------------------------
// raw (fp32|bf16) -> fp16
// ---------------------------------------------------------------------------
__global__ __launch_bounds__(256) void cvt_half_kernel(const void* __restrict__ in_raw,
                                                       _Float16* __restrict__ out, long n,
                                                       const int* __restrict__ flag) {
    const int is_bf16 = *flag;
    long i = ((long)blockIdx.x * 256 + threadIdx.x) * 8;
    if (i >= n) return;
    F8 x = load8(in_raw, i, is_bf16);
    half8 o;
    #pragma unroll
    for (int j = 0; j < 8; ++j) o[j] = (_Float16)x.v[j];
    *reinterpret_cast<half8*>(out + i) = o;
}

// ---------------------------------------------------------------------------
// Kernel 1: Q = F @ Wq^T + bq ; K = F @ Wk^T + bk  (fp16 MFMA, fp16 out)
// Block 256 = 4 waves; 16 rows x (Q 128 cols | K 128 cols).
// ---------------------------------------------------------------------------
__global__ __launch_bounds__(256) void proj_kernel(
    const void* __restrict__ Fraw,        // [B*N, C] fp32 or bf16
    const _Float16* __restrict__ Wq_h,    // [D, C] fp16
    const void* __restrict__ bq_raw,
    const _Float16* __restrict__ Wk_h,    // [D, C] fp16
    const void* __restrict__ bk_raw,
    _Float16* __restrict__ Q, _Float16* __restrict__ K,
    const int* __restrict__ flag)
{
    const int is_bf16 = *flag;
    const int wave = threadIdx.x >> 6;
    const int lane = threadIdx.x & 63;
    const int quad = lane >> 4;
    const int l16  = lane & 15;
    const long row0 = (long)blockIdx.x * 16;

    const bool isK = (wave >= 2);
    const _Float16* W = isK ? Wk_h : Wq_h;
    const void* braw  = isK ? bk_raw : bq_raw;
    _Float16* Out     = isK ? K : Q;
    const int dbase   = (wave & 1) * 64;

    floatx4 acc[4] = {};
    const long arow = (row0 + l16) * (long)C_ + quad * 8;

    for (int s = 0; s < 32; ++s) {
        F8 x = load8(Fraw, arow + s * 32, is_bf16);
        half8 a;
        #pragma unroll
        for (int j = 0; j < 8; ++j) a[j] = (_Float16)x.v[j];
        #pragma unroll
        for (int t = 0; t < 4; ++t) {
            const long woff = (long)(dbase + t * 16 + l16) * C_ + s * 32 + quad * 8;
            half8 b = *reinterpret_cast<const half8*>(W + woff);
            acc[t] = __builtin_amdgcn_mfma_f32_16x16x32_f16(a, b, acc[t], 0, 0, 0);
        }
    }

    #pragma unroll
    for (int t = 0; t < 4; ++t) {
        const int d = dbase + t * 16 + l16;
        const float bv = bias_at(braw, d, is_bf16);
        #pragma unroll
        for (int r = 0; r < 4; ++r) {
            const long row = row0 + quad * 4 + r;
            Out[row * D_ + d] = (_Float16)(acc[t][r] + bv);
        }
    }
}

// ---------------------------------------------------------------------------
// Kernel 2: E = Q K^T ; softmax rows -> A (bf16 bits)
// Block 512 = 8 waves, covers 32 rows x 2048 cols; wave w: cols [w*256, w*256+256).
// Each K-frag feeds 2 row-group MFMAs.
// ---------------------------------------------------------------------------
__global__ __launch_bounds__(512) void attn_kernel(
    const _Float16* __restrict__ Q,   // [B, N, D]
    const _Float16* __restrict__ K,   // [B, N, D]
    short* __restrict__ A)            // [B, N, N] bf16 bits
{
    const int b    = blockIdx.y;
    const int i0   = blockIdx.x * 32;
    const int wave = threadIdx.x >> 6;
    const int lane = threadIdx.x & 63;
    const int quad = lane >> 4;
    const int l16  = lane & 15;

    const _Float16* Qb = Q + (long)b * N_ * D_;
    const _Float16* Kb = K + (long)b * N_ * D_;

    half8 a[2][4];
    #pragma unroll
    for (int v = 0; v < 2; ++v)
        #pragma unroll
        for (int s = 0; s < 4; ++s)
            a[v][s] = *reinterpret_cast<const half8*>(
                Qb + (long)(i0 + v * 16 + l16) * D_ + s * 32 + quad * 8);

    floatx4 acc[2][16];
    #pragma unroll
    for (int v = 0; v < 2; ++v)
        #pragma unroll
        for (int t = 0; t < 16; ++t) acc[v][t] = (floatx4){0.f, 0.f, 0.f, 0.f};

    const int jbase = wave * 256;
    #pragma unroll
    for (int t = 0; t < 16; ++t) {
        const _Float16* krow = Kb + (long)(jbase + t * 16 + l16) * D_ + quad * 8;
        #pragma unroll
        for (int s = 0; s < 4; ++s) {
            half8 kf = *reinterpret_cast<const half8*>(krow + s * 32);
            acc[0][t] = __builtin_amdgcn_mfma_f32_16x16x32_f16(a[0][s], kf, acc[0][t], 0, 0, 0);
            acc[1][t] = __builtin_amdgcn_mfma_f32_16x16x32_f16(a[1][s], kf, acc[1][t], 0, 0, 0);
        }
    }

    __shared__ float red[32][8];
    float gmax[2][4], inv[2][4];

    #pragma unroll
    for (int v = 0; v < 2; ++v)
        #pragma unroll
        for (int r = 0; r < 4; ++r) {
            float m = -1e30f;
            #pragma unroll
            for (int t = 0; t < 16; ++t) m = fmaxf(m, acc[v][t][r]);
            m = fmaxf(m, __shfl_xor(m, 1));
            m = fmaxf(m, __shfl_xor(m, 2));
            m = fmaxf(m, __shfl_xor(m, 4));
            m = fmaxf(m, __shfl_xor(m, 8));
            if (l16 == 0) red[v * 16 + quad * 4 + r][wave] = m;
        }
    __syncthreads();
    #pragma unroll
    for (int v = 0; v < 2; ++v)
        #pragma unroll
        for (int r = 0; r < 4; ++r) {
            float m = red[v * 16 + quad * 4 + r][0];
            #pragma unroll
            for (int w = 1; w < 8; ++w) m = fmaxf(m, red[v * 16 + quad * 4 + r][w]);
            gmax[v][r] = m;
        }
    __syncthreads();

    #pragma unroll
    for (int v = 0; v < 2; ++v)
        #pragma unroll
        for (int r = 0; r < 4; ++r) {
            float s = 0.f;
            #pragma unroll
            for (int t = 0; t < 16; ++t) {
                float e = __expf(acc[v][t][r] - gmax[v][r]);
                acc[v][t][r] = e;
                s += e;
            }
            s += __shfl_xor(s, 1);
            s += __shfl_xor(s, 2);
            s += __shfl_xor(s, 4);
            s += __shfl_xor(s, 8);
            if (l16 == 0) red[v * 16 + quad * 4 + r][wave] = s;
        }
    __syncthreads();
    #pragma unroll
    for (int v = 0; v < 2; ++v)
        #pragma unroll
        for (int r = 0; r < 4; ++r) {
            float s = 0.f;
            #pragma unroll
            for (int w = 0; w < 8; ++w) s += red[v * 16 + quad * 4 + r][w];
            inv[v][r] = 1.0f / s;
        }

    short* Ab = A + (long)b * N_ * N_;
    #pragma unroll
    for (int v = 0; v < 2; ++v)
        #pragma unroll
        for (int t = 0; t < 16; ++t) {
            const int j = jbase + t * 16 + l16;
            #pragma unroll
            for (int r = 0; r < 4; ++r) {
                Ab[(long)(i0 + v * 16 + quad * 4 + r) * N_ + j] =
                    f2bf(acc[v][t][r] * inv[v][r]);
            }
        }
}

// ---------------------------------------------------------------------------
// Kernel 3: x_m[b,l,m] = sum_n logits[b,l,n] * A[b,m,n]
// m97-style: 128x128 block tile, BK=32, LDS staged via global_load_lds(16B).
// 256 thr = 4 waves; wave computes 64x64 (4x4 accs of 16x16x32 bf16 MFMA).
// ---------------------------------------------------------------------------
__global__ __launch_bounds__(256) void xm_kernel(
    const short* __restrict__ Lg,   // [B, L, N] bf16 bits
    const short* __restrict__ A,    // [B, N, N] bf16 bits
    void* __restrict__ OutRaw,
    const int* __restrict__ flag)
{
    const int is_bf16 = *flag;
    const int b  = blockIdx.z;
    const int r0 = blockIdx.x * 128;   // logits rows (L=512): gridDim.x = 4
    const int c0 = blockIdx.y * 128;   // output cols (N=2048): gridDim.y = 16
    const int wave = threadIdx.x >> 6;
    const int lane = threadIdx.x & 63;
    const int quad = lane >> 4;
    const int l16  = lane & 15;

    __shared__ short Atile[128 * 32];  // logits tile [row][k]
    __shared__ short Btile[128 * 32];  // A tile [col-row][k]

    const short* Lb = Lg + (long)b * L_ * N_;
    const short* Ab = A  + (long)b * N_ * N_;

    const int m0 = (wave & 1) * 64;
    const int n0 = (wave >> 1) * 64;

    floatx4 acc[4][4] = {};

    const int srow  = lane >> 2;        // 0..15 within chunk
    const int skoff = (lane & 3) * 8;   // 0,8,16,24

    for (int kb = 0; kb < 64; ++kb) {
        const int k0 = kb * 32;
        // stage: 16 chunks of 1 KB (64 lanes x 16 B); wave stages 4 chunks
        #pragma unroll
        for (int j = 0; j < 4; ++j) {
            const int cc = wave * 4 + j;             // 0..15
            if (cc < 8) {
                const short* src = Lb + (long)(r0 + cc * 16 + srow) * N_ + k0 + skoff;
                load_lds16(src, Atile + cc * 512);
            } else {
                const int c8 = cc - 8;
                const short* src = Ab + (long)(c0 + c8 * 16 + srow) * N_ + k0 + skoff;
                load_lds16(src, Btile + c8 * 512);
            }
        }
        __syncthreads();   // drains vmcnt -> staged data visible

        short8 af[4], bf[4];
        #pragma unroll
        for (int t = 0; t < 4; ++t)
            af[t] = *reinterpret_cast<const short8*>(Atile + (m0 + t * 16 + l16) * 32 + quad * 8);
        #pragma unroll
        for (int u = 0; u < 4; ++u)
            bf[u] = *reinterpret_cast<const short8*>(Btile + (n0 + u * 16 + l16) * 32 + quad * 8);

        #pragma unroll
        for (int t = 0; t < 4; ++t)
            #pragma unroll
            for (int u = 0; u < 4; ++u)
                acc[t][u] = __builtin_amdgcn_mfma_f32_16x16x32_bf16(af[t], bf[u], acc[t][u], 0, 0, 0);

        __syncthreads();   // protect LDS before next stage
    }

    if (is_bf16) {
        short* Ob = (short*)OutRaw + (long)b * L_ * N_;
        #pragma unroll
        for (int t = 0; t < 4; ++t)
            #pragma unroll
            for (int u = 0; u < 4; ++u)
                #pragma unroll
                for (int r = 0; r < 4; ++r) {
                    const long row = r0 + m0 + t * 16 + quad * 4 + r;
                    const int  col = c0 + n0 + u * 16 + l16;
                    Ob[row * N_ + col] = f2bf(acc[t][u][r]);
                }
    } else {
        float* Ob = (float*)OutRaw + (long)b * L_ * N_;
        #pragma unroll
        for (int t = 0; t < 4; ++t)
            #pragma unroll
            for (int u = 0; u < 4; ++u)
                #pragma unroll
                for (int r = 0; r < 4; ++r) {
                    const long row = r0 + m0 + t * 16 + quad * 4 + r;
                    const int  col = c0 + n0 + u * 16 + l16;
                    Ob[row * N_ + col] = acc[t][u][r];
                }
    }
}

// ---------------------------------------------------------------------------
extern "C" void kernel_launch(void* const* d_in, const int* in_sizes, int n_in,
                              void* d_out, int out_size, void* d_ws, size_t ws_size,
                              hipStream_t stream) {
    const void* logits_raw = d_in[0];  // [B,L,N]
    const void* feats_raw  = d_in[1];  // [B,N,C]
    const void* wq_raw     = d_in[2];  // [D,C]
    const void* bq_raw     = d_in[3];  // [D]
    const void* wk_raw     = d_in[4];  // [D,C]
    const void* bk_raw     = d_in[5];  // [D]

    char* ws = (char*)d_ws;
    size_t off = 0;
    int* flag = (int*)(ws + off);           off += 256;
    short* logb = (short*)(ws + off);       off += (size_t)B_ * L_ * N_ * 2;   // 16 MB
    _Float16* Wq_h = (_Float16*)(ws + off); off += (size_t)D_ * C_ * 2;
    _Float16* Wk_h = (_Float16*)(ws + off); off += (size_t)D_ * C_ * 2;
    _Float16* Q = (_Float16*)(ws + off);    off += (size_t)B_ * N_ * D_ * 2;   // 4 MB
    _Float16* K = (_Float16*)(ws + off);    off += (size_t)B_ * N_ * D_ * 2;   // 4 MB
    short* A = (short*)(ws + off);          off += (size_t)B_ * N_ * N_ * 2;   // 67 MB

    hipLaunchKernelGGL(detect_kernel, dim3(1), dim3(64), 0, stream,
                       (const unsigned*)feats_raw, flag);
    hipLaunchKernelGGL(cvt_kernel, dim3((B_ * L_ * N_) / (256 * 8)), dim3(256), 0, stream,
                       logits_raw, logb, (long)B_ * L_ * N_, flag);
    hipLaunchKernelGGL(cvt_half_kernel, dim3((D_ * C_) / (256 * 8)), dim3(256), 0, stream,
                       wq_raw, Wq_h, (long)D_ * C_, flag);
    hipLaunchKernelGGL(cvt_half_kernel, dim3((D_ * C_) / (256 * 8)), dim3(256), 0, stream,
                       wk_raw, Wk_h, (long)D_ * C_, flag);
    hipLaunchKernelGGL(proj_kernel, dim3(B_ * N_ / 16), dim3(256), 0, stream,
                       feats_raw, Wq_h, bq_raw, Wk_h, bk_raw, Q, K, flag);
    hipLaunchKernelGGL(attn_kernel, dim3(N_ / 32, B_), dim3(512), 0, stream,
                       Q, K, A);
    hipLaunchKernelGGL(xm_kernel, dim3(L_ / 128, N_ / 128, B_), dim3(256), 0, stream,
                       logb, A, d_out, flag);
}

// Round 4
// 285.398 us; speedup vs baseline: 1.8283x; 1.1782x over previous
//
#include <hip/hip_runtime.h>
#include <hip/hip_bf16.h>

#define B_ 8
#define L_ 512
#define N_ 2048
#define C_ 1024
#define D_ 128

typedef __attribute__((ext_vector_type(8))) short    short8;   // 8 x bf16 bits
typedef __attribute__((ext_vector_type(8))) _Float16 half8;
typedef __attribute__((ext_vector_type(4))) float    floatx4;

static __device__ __forceinline__ float s2f(short s) {
    return __uint_as_float(((unsigned)(unsigned short)s) << 16);
}
static __device__ __forceinline__ short f2bf(float f) {
    union { __hip_bfloat16 h; short s; } u;
    u.h = __float2bfloat16(f);
    return u.s;
}

struct F8 { float v[8]; };

// Load 8 consecutive elements from a raw input buffer that is either fp32 or
// bf16 (flag is wave-uniform), returning fp32 values.
static __device__ __forceinline__ F8 load8(const void* raw, long off, int is_bf16) {
    F8 r;
    if (is_bf16) {
        short8 x = *reinterpret_cast<const short8*>((const short*)raw + off);
        #pragma unroll
        for (int i = 0; i < 8; ++i) r.v[i] = s2f(x[i]);
    } else {
        const float* p = (const float*)raw + off;
        float4 a = *reinterpret_cast<const float4*>(p);
        float4 b = *reinterpret_cast<const float4*>(p + 4);
        r.v[0]=a.x; r.v[1]=a.y; r.v[2]=a.z; r.v[3]=a.w;
        r.v[4]=b.x; r.v[5]=b.y; r.v[6]=b.z; r.v[7]=b.w;
    }
    return r;
}

static __device__ __forceinline__ float bias_at(const void* raw, int d, int is_bf16) {
    return is_bf16 ? s2f(((const short*)raw)[d]) : ((const float*)raw)[d];
}

static __device__ __forceinline__ void load_lds16(const void* g, void* l) {
    __builtin_amdgcn_global_load_lds(
        (const __attribute__((address_space(1))) void*)g,
        (__attribute__((address_space(3))) void*)l, 16, 0, 0);
}

// ---------------------------------------------------------------------------
// Dtype detection (fp32 vs bf16 world).
// ---------------------------------------------------------------------------
__global__ void detect_kernel(const unsigned* __restrict__ words, int* __restrict__ flag) {
    int cnt = 0;
    for (int i = threadIdx.x; i < 256; i += 64) {
        float lowv = __uint_as_float(words[i] << 16);
        float a = fabsf(lowv);
        if (a >= 1e-5f && a <= 100.0f) cnt++;
    }
    #pragma unroll
    for (int off = 32; off; off >>= 1) cnt += __shfl_down(cnt, off);
    if (threadIdx.x == 0) flag[0] = (cnt > 128) ? 1 : 0;
}

// ---------------------------------------------------------------------------
// raw (fp32|bf16) -> bf16 bits
// ---------------------------------------------------------------------------
__global__ __launch_bounds__(256) void cvt_kernel(const void* __restrict__ in_raw,
                                                  short* __restrict__ out, long n,
                                                  const int* __restrict__ flag) {
    const int is_bf16 = *flag;
    long i = ((long)blockIdx.x * 256 + threadIdx.x) * 8;
    if (i >= n) return;
    F8 x = load8(in_raw, i, is_bf16);
    short8 o;
    #pragma unroll
    for (int j = 0; j < 8; ++j) o[j] = f2bf(x.v[j]);
    *reinterpret_cast<short8*>(out + i) = o;
}

// ---------------------------------------------------------------------------
// raw (fp32|bf16) -> fp16  (exact for bf16 inputs in our value range)
// ---------------------------------------------------------------------------
__global__ __launch_bounds__(256) void cvt_half_kernel(const void* __restrict__ in_raw,
                                                       _Float16* __restrict__ out, long n,
                                                       const int* __restrict__ flag) {
    const int is_bf16 = *flag;
    long i = ((long)blockIdx.x * 256 + threadIdx.x) * 8;
    if (i >= n) return;
    F8 x = load8(in_raw, i, is_bf16);
    half8 o;
    #pragma unroll
    for (int j = 0; j < 8; ++j) o[j] = (_Float16)x.v[j];
    *reinterpret_cast<half8*>(out + i) = o;
}

// ---------------------------------------------------------------------------
// Kernel 1: Q = F @ Wq^T + bq ; K = F @ Wk^T + bk  (fp16 MFMA, fp16 out)
// m97-style LDS GEMM: block tile 128 rows x 128 dims, BK=32, 512 thr = 8 waves,
// wave tile 32x64 (2x4 accs). blockIdx.y: 0 -> Q, 1 -> K.
// F tile staged via vector-load + cvt fp16 + ds_write; W tile via global_load_lds.
// ---------------------------------------------------------------------------
__global__ __launch_bounds__(512) void proj_kernel(
    const void* __restrict__ Fraw,        // [B*N, C] fp32 or bf16
    const _Float16* __restrict__ Wq_h,    // [D, C] fp16
    const void* __restrict__ bq_raw,
    const _Float16* __restrict__ Wk_h,    // [D, C] fp16
    const void* __restrict__ bk_raw,
    _Float16* __restrict__ Q, _Float16* __restrict__ K,
    const int* __restrict__ flag)
{
    const int is_bf16 = *flag;
    const int tid  = threadIdx.x;
    const int wave = tid >> 6;
    const int lane = tid & 63;
    const int quad = lane >> 4;
    const int l16  = lane & 15;
    const long r0  = (long)blockIdx.x * 128;

    const bool isK = (blockIdx.y != 0);
    const _Float16* W = isK ? Wk_h : Wq_h;
    const void* braw  = isK ? bk_raw : bq_raw;
    _Float16* Out     = isK ? K : Q;

    const int m0 = (wave & 3) * 32;   // rows within tile
    const int n0 = (wave >> 2) * 64;  // dims within tile

    __shared__ _Float16 Ft[128 * 32]; // 8 KB [row][k]
    __shared__ _Float16 Wt[128 * 32]; // 8 KB [d][k]

    floatx4 acc[2][4] = {};

    // F staging map: thread tid loads 8 elems: row = tid>>2, koff = (tid&3)*8
    const int frow  = tid >> 2;
    const int fkoff = (tid & 3) * 8;
    // W staging map: wave w stages chunk w (16 d-rows)
    const int wsrow  = lane >> 2;
    const int wskoff = (lane & 3) * 8;

    for (int kb = 0; kb < 32; ++kb) {
        const int k0 = kb * 32;

        // stage W chunk: rows wave*16..+16, k0..k0+32 -> Wt + wave*512 + lane*8
        load_lds16(W + (long)(wave * 16 + wsrow) * C_ + k0 + wskoff,
                   Wt + wave * 512 + lane * 8);

        // stage F: 128x32 = 4096 elems, 8 per thread, cvt to fp16
        {
            F8 x = load8(Fraw, (r0 + frow) * (long)C_ + k0 + fkoff, is_bf16);
            half8 h;
            #pragma unroll
            for (int j = 0; j < 8; ++j) h[j] = (_Float16)x.v[j];
            *reinterpret_cast<half8*>(Ft + tid * 8) = h;
        }
        __syncthreads();

        half8 af[2], bf[4];
        #pragma unroll
        for (int t = 0; t < 2; ++t)
            af[t] = *reinterpret_cast<const half8*>(Ft + (m0 + t * 16 + l16) * 32 + quad * 8);
        #pragma unroll
        for (int u = 0; u < 4; ++u)
            bf[u] = *reinterpret_cast<const half8*>(Wt + (n0 + u * 16 + l16) * 32 + quad * 8);

        #pragma unroll
        for (int t = 0; t < 2; ++t)
            #pragma unroll
            for (int u = 0; u < 4; ++u)
                acc[t][u] = __builtin_amdgcn_mfma_f32_16x16x32_f16(af[t], bf[u], acc[t][u], 0, 0, 0);

        __syncthreads();
    }

    #pragma unroll
    for (int u = 0; u < 4; ++u) {
        const int d = n0 + u * 16 + l16;
        const float bv = bias_at(braw, d, is_bf16);
        #pragma unroll
        for (int t = 0; t < 2; ++t)
            #pragma unroll
            for (int r = 0; r < 4; ++r) {
                const long row = r0 + m0 + t * 16 + quad * 4 + r;
                Out[row * D_ + d] = (_Float16)(acc[t][u][r] + bv);
            }
    }
}

// ---------------------------------------------------------------------------
// Kernel 2: E = Q K^T ; softmax rows -> A (bf16 bits)
// Block 512 = 8 waves, covers 32 rows x 2048 cols; wave w: cols [w*256, w*256+256).
// ---------------------------------------------------------------------------
__global__ __launch_bounds__(512) void attn_kernel(
    const _Float16* __restrict__ Q,   // [B, N, D]
    const _Float16* __restrict__ K,   // [B, N, D]
    short* __restrict__ A)            // [B, N, N] bf16 bits
{
    const int b    = blockIdx.y;
    const int i0   = blockIdx.x * 32;
    const int wave = threadIdx.x >> 6;
    const int lane = threadIdx.x & 63;
    const int quad = lane >> 4;
    const int l16  = lane & 15;

    const _Float16* Qb = Q + (long)b * N_ * D_;
    const _Float16* Kb = K + (long)b * N_ * D_;

    half8 a[2][4];
    #pragma unroll
    for (int v = 0; v < 2; ++v)
        #pragma unroll
        for (int s = 0; s < 4; ++s)
            a[v][s] = *reinterpret_cast<const half8*>(
                Qb + (long)(i0 + v * 16 + l16) * D_ + s * 32 + quad * 8);

    floatx4 acc[2][16];
    #pragma unroll
    for (int v = 0; v < 2; ++v)
        #pragma unroll
        for (int t = 0; t < 16; ++t) acc[v][t] = (floatx4){0.f, 0.f, 0.f, 0.f};

    const int jbase = wave * 256;
    #pragma unroll
    for (int t = 0; t < 16; ++t) {
        const _Float16* krow = Kb + (long)(jbase + t * 16 + l16) * D_ + quad * 8;
        #pragma unroll
        for (int s = 0; s < 4; ++s) {
            half8 kf = *reinterpret_cast<const half8*>(krow + s * 32);
            acc[0][t] = __builtin_amdgcn_mfma_f32_16x16x32_f16(a[0][s], kf, acc[0][t], 0, 0, 0);
            acc[1][t] = __builtin_amdgcn_mfma_f32_16x16x32_f16(a[1][s], kf, acc[1][t], 0, 0, 0);
        }
    }

    __shared__ float red[32][8];
    float gmax[2][4], inv[2][4];

    #pragma unroll
    for (int v = 0; v < 2; ++v)
        #pragma unroll
        for (int r = 0; r < 4; ++r) {
            float m = -1e30f;
            #pragma unroll
            for (int t = 0; t < 16; ++t) m = fmaxf(m, acc[v][t][r]);
            m = fmaxf(m, __shfl_xor(m, 1));
            m = fmaxf(m, __shfl_xor(m, 2));
            m = fmaxf(m, __shfl_xor(m, 4));
            m = fmaxf(m, __shfl_xor(m, 8));
            if (l16 == 0) red[v * 16 + quad * 4 + r][wave] = m;
        }
    __syncthreads();
    #pragma unroll
    for (int v = 0; v < 2; ++v)
        #pragma unroll
        for (int r = 0; r < 4; ++r) {
            float m = red[v * 16 + quad * 4 + r][0];
            #pragma unroll
            for (int w = 1; w < 8; ++w) m = fmaxf(m, red[v * 16 + quad * 4 + r][w]);
            gmax[v][r] = m;
        }
    __syncthreads();

    #pragma unroll
    for (int v = 0; v < 2; ++v)
        #pragma unroll
        for (int r = 0; r < 4; ++r) {
            float s = 0.f;
            #pragma unroll
            for (int t = 0; t < 16; ++t) {
                float e = __expf(acc[v][t][r] - gmax[v][r]);
                acc[v][t][r] = e;
                s += e;
            }
            s += __shfl_xor(s, 1);
            s += __shfl_xor(s, 2);
            s += __shfl_xor(s, 4);
            s += __shfl_xor(s, 8);
            if (l16 == 0) red[v * 16 + quad * 4 + r][wave] = s;
        }
    __syncthreads();
    #pragma unroll
    for (int v = 0; v < 2; ++v)
        #pragma unroll
        for (int r = 0; r < 4; ++r) {
            float s = 0.f;
            #pragma unroll
            for (int w = 0; w < 8; ++w) s += red[v * 16 + quad * 4 + r][w];
            inv[v][r] = 1.0f / s;
        }

    short* Ab = A + (long)b * N_ * N_;
    #pragma unroll
    for (int v = 0; v < 2; ++v)
        #pragma unroll
        for (int t = 0; t < 16; ++t) {
            const int j = jbase + t * 16 + l16;
            #pragma unroll
            for (int r = 0; r < 4; ++r) {
                Ab[(long)(i0 + v * 16 + quad * 4 + r) * N_ + j] =
                    f2bf(acc[v][t][r] * inv[v][r]);
            }
        }
}

// ---------------------------------------------------------------------------
// Kernel 3: x_m[b,l,m] = sum_n logits[b,l,n] * A[b,m,n]
// m97-style: 128x128 block tile, BK=32, LDS staged via global_load_lds(16B).
// 256 thr = 4 waves; wave computes 64x64 (4x4 accs of 16x16x32 bf16 MFMA).
// ---------------------------------------------------------------------------
__global__ __launch_bounds__(256) void xm_kernel(
    const short* __restrict__ Lg,   // [B, L, N] bf16 bits
    const short* __restrict__ A,    // [B, N, N] bf16 bits
    void* __restrict__ OutRaw,
    const int* __restrict__ flag)
{
    const int is_bf16 = *flag;
    const int b  = blockIdx.z;
    const int r0 = blockIdx.x * 128;   // logits rows (L=512): gridDim.x = 4
    const int c0 = blockIdx.y * 128;   // output cols (N=2048): gridDim.y = 16
    const int wave = threadIdx.x >> 6;
    const int lane = threadIdx.x & 63;
    const int quad = lane >> 4;
    const int l16  = lane & 15;

    __shared__ short Atile[128 * 32];  // logits tile [row][k]
    __shared__ short Btile[128 * 32];  // A tile [col-row][k]

    const short* Lb = Lg + (long)b * L_ * N_;
    const short* Ab = A  + (long)b * N_ * N_;

    const int m0 = (wave & 1) * 64;
    const int n0 = (wave >> 1) * 64;

    floatx4 acc[4][4] = {};

    const int srow  = lane >> 2;        // 0..15 within chunk
    const int skoff = (lane & 3) * 8;   // 0,8,16,24

    for (int kb = 0; kb < 64; ++kb) {
        const int k0 = kb * 32;
        #pragma unroll
        for (int j = 0; j < 4; ++j) {
            const int cc = wave * 4 + j;             // 0..15
            if (cc < 8) {
                const short* src = Lb + (long)(r0 + cc * 16 + srow) * N_ + k0 + skoff;
                load_lds16(src, Atile + cc * 512);
            } else {
                const int c8 = cc - 8;
                const short* src = Ab + (long)(c0 + c8 * 16 + srow) * N_ + k0 + skoff;
                load_lds16(src, Btile + c8 * 512);
            }
        }
        __syncthreads();

        short8 af[4], bf[4];
        #pragma unroll
        for (int t = 0; t < 4; ++t)
            af[t] = *reinterpret_cast<const short8*>(Atile + (m0 + t * 16 + l16) * 32 + quad * 8);
        #pragma unroll
        for (int u = 0; u < 4; ++u)
            bf[u] = *reinterpret_cast<const short8*>(Btile + (n0 + u * 16 + l16) * 32 + quad * 8);

        #pragma unroll
        for (int t = 0; t < 4; ++t)
            #pragma unroll
            for (int u = 0; u < 4; ++u)
                acc[t][u] = __builtin_amdgcn_mfma_f32_16x16x32_bf16(af[t], bf[u], acc[t][u], 0, 0, 0);

        __syncthreads();
    }

    if (is_bf16) {
        short* Ob = (short*)OutRaw + (long)b * L_ * N_;
        #pragma unroll
        for (int t = 0; t < 4; ++t)
            #pragma unroll
            for (int u = 0; u < 4; ++u)
                #pragma unroll
                for (int r = 0; r < 4; ++r) {
                    const long row = r0 + m0 + t * 16 + quad * 4 + r;
                    const int  col = c0 + n0 + u * 16 + l16;
                    Ob[row * N_ + col] = f2bf(acc[t][u][r]);
                }
    } else {
        float* Ob = (float*)OutRaw + (long)b * L_ * N_;
        #pragma unroll
        for (int t = 0; t < 4; ++t)
            #pragma unroll
            for (int u = 0; u < 4; ++u)
                #pragma unroll
                for (int r = 0; r < 4; ++r) {
                    const long row = r0 + m0 + t * 16 + quad * 4 + r;
                    const int  col = c0 + n0 + u * 16 + l16;
                    Ob[row * N_ + col] = acc[t][u][r];
                }
    }
}

// ---------------------------------------------------------------------------
extern "C" void kernel_launch(void* const* d_in, const int* in_sizes, int n_in,
                              void* d_out, int out_size, void* d_ws, size_t ws_size,
                              hipStream_t stream) {
    const void* logits_raw = d_in[0];  // [B,L,N]
    const void* feats_raw  = d_in[1];  // [B,N,C]
    const void* wq_raw     = d_in[2];  // [D,C]
    const void* bq_raw     = d_in[3];  // [D]
    const void* wk_raw     = d_in[4];  // [D,C]
    const void* bk_raw     = d_in[5];  // [D]

    char* ws = (char*)d_ws;
    size_t off = 0;
    int* flag = (int*)(ws + off);           off += 256;
    short* logb = (short*)(ws + off);       off += (size_t)B_ * L_ * N_ * 2;   // 16 MB
    _Float16* Wq_h = (_Float16*)(ws + off); off += (size_t)D_ * C_ * 2;
    _Float16* Wk_h = (_Float16*)(ws + off); off += (size_t)D_ * C_ * 2;
    _Float16* Q = (_Float16*)(ws + off);    off += (size_t)B_ * N_ * D_ * 2;   // 4 MB
    _Float16* K = (_Float16*)(ws + off);    off += (size_t)B_ * N_ * D_ * 2;   // 4 MB
    short* A = (short*)(ws + off);          off += (size_t)B_ * N_ * N_ * 2;   // 67 MB

    hipLaunchKernelGGL(detect_kernel, dim3(1), dim3(64), 0, stream,
                       (const unsigned*)feats_raw, flag);
    hipLaunchKernelGGL(cvt_kernel, dim3((B_ * L_ * N_) / (256 * 8)), dim3(256), 0, stream,
                       logits_raw, logb, (long)B_ * L_ * N_, flag);
    hipLaunchKernelGGL(cvt_half_kernel, dim3((D_ * C_) / (256 * 8)), dim3(256), 0, stream,
                       wq_raw, Wq_h, (long)D_ * C_, flag);
    hipLaunchKernelGGL(cvt_half_kernel, dim3((D_ * C_) / (256 * 8)), dim3(256), 0, stream,
                       wk_raw, Wk_h, (long)D_ * C_, flag);
    hipLaunchKernelGGL(proj_kernel, dim3(B_ * N_ / 128, 2), dim3(512), 0, stream,
                       feats_raw, Wq_h, bq_raw, Wk_h, bk_raw, Q, K, flag);
    hipLaunchKernelGGL(attn_kernel, dim3(N_ / 32, B_), dim3(512), 0, stream,
                       Q, K, A);
    hipLaunchKernelGGL(xm_kernel, dim3(L_ / 128, N_ / 128, B_), dim3(256), 0, stream,
                       logb, A, d_out, flag);
}